// Round 10
// baseline (246.246 us; speedup 1.0000x reference)
//
#include <hip/hip_runtime.h>
#include <cstdint>

#define N_TOT 1572864
#define KSEL 4096
#define CAP 8192
#define BINS 4096
#define SCORE_THR 0.5f
#define IOU_THR 0.1f
#define STREAM_BLOCKS 512
#define STAGE 512

__device__ inline uint64_t readlane64(uint64_t v, int lane) {
    uint32_t lo = (uint32_t)__builtin_amdgcn_readlane((int)(uint32_t)v, lane);
    uint32_t hi = (uint32_t)__builtin_amdgcn_readlane((int)(uint32_t)(v >> 32), lane);
    return ((uint64_t)hi << 32) | lo;
}

// ---------------- init: zero hist/counters/topScore ----------------
__global__ void k_init(uint32_t* hist, uint32_t* ctrs, float* topScore) {
    int i = blockIdx.x * blockDim.x + threadIdx.x;
    if (i < BINS) hist[i] = 0;
    if (i < 16) ctrs[i] = 0;
    if (i < KSEL) topScore[i] = 0.0f;
}

// ---------------- histogram over score bits (scores in (0.5,1)), float4 stream ----------------
__global__ void k_hist(const float4* __restrict__ cls4, uint32_t* __restrict__ hist) {
    int i = blockIdx.x * blockDim.x + threadIdx.x;
    int stride = gridDim.x * blockDim.x;
    for (; i < N_TOT / 2; i += stride) {
        float4 c = cls4[i];
        if (c.y > SCORE_THR) {
            uint32_t bin = (__float_as_uint(c.y) - 0x3F000000u) >> 11;
            if (bin >= BINS) bin = BINS - 1;
            atomicAdd(&hist[bin], 1u);
        }
        if (c.w > SCORE_THR) {
            uint32_t bin = (__float_as_uint(c.w) - 0x3F000000u) >> 11;
            if (bin >= BINS) bin = BINS - 1;
            atomicAdd(&hist[bin], 1u);
        }
    }
}

// ---------------- find cutoff bin T: largest b with suffix(b) >= K ----------------
__global__ __launch_bounds__(1024) void k_thresh(const uint32_t* __restrict__ hist,
                                                 uint32_t* __restrict__ ctrs) {
    __shared__ uint32_t s_suf[1024];
    int t = threadIdx.x;
    uint32_t l0 = hist[t*4+0], l1 = hist[t*4+1], l2 = hist[t*4+2], l3 = hist[t*4+3];
    s_suf[t] = l0 + l1 + l2 + l3;
    __syncthreads();
    for (int off = 1; off < 1024; off <<= 1) {
        uint32_t v = (t + off < 1024) ? s_suf[t + off] : 0u;
        __syncthreads();
        s_suf[t] += v;
        __syncthreads();
    }
    uint32_t snext = (t < 1023) ? s_suf[t + 1] : 0u;
    uint32_t suf3 = snext + l3;
    uint32_t suf2 = suf3 + l2;
    uint32_t suf1 = suf2 + l1;
    uint32_t suf0 = suf1 + l0;
    uint32_t sufs[5] = {suf0, suf1, suf2, suf3, snext};
    #pragma unroll
    for (int q = 0; q < 4; q++) {
        if (sufs[q] >= KSEL && sufs[q+1] < KSEL) ctrs[1] = (uint32_t)(t*4 + q);
    }
    if (t == 0 && s_suf[0] < KSEL) ctrs[1] = 0;  // fewer than K candidates
}

// ---------------- gather candidates (bin >= T) via LDS staging; 1 global atomic/block ----------------
__global__ void k_gather(const float4* __restrict__ cls4, uint32_t* __restrict__ ctrs,
                         uint64_t* __restrict__ keys) {
    __shared__ uint32_t s_cnt;
    __shared__ uint32_t s_base;
    __shared__ uint64_t s_stage[STAGE];
    if (threadIdx.x == 0) s_cnt = 0;
    __syncthreads();

    uint32_t T = ctrs[1];
    uint32_t basebits = 0x3F000000u + (T << 11);
    int i = blockIdx.x * blockDim.x + threadIdx.x;
    int stride = gridDim.x * blockDim.x;
    for (; i < N_TOT / 2; i += stride) {
        float4 c = cls4[i];
        #pragma unroll
        for (int h = 0; h < 2; h++) {
            float s = h ? c.w : c.y;
            uint32_t idx = 2u * (uint32_t)i + (uint32_t)h;
            if (s > SCORE_THR) {
                uint32_t b = __float_as_uint(s);
                if (b >= basebits) {
                    uint64_t key = ((uint64_t)b << 32) | (uint32_t)(~idx);
                    uint32_t p = atomicAdd(&s_cnt, 1u);
                    if (p < STAGE) s_stage[p] = key;
                    else {  // overflow: rare fallback, correctness-preserving
                        uint32_t g = atomicAdd(&ctrs[0], 1u);
                        if (g < CAP) keys[g] = key;
                    }
                }
            }
        }
    }
    __syncthreads();
    uint32_t n = s_cnt < STAGE ? s_cnt : STAGE;
    if (threadIdx.x == 0 && n > 0) s_base = atomicAdd(&ctrs[0], n);
    __syncthreads();
    for (uint32_t q = threadIdx.x; q < n; q += blockDim.x) {
        uint32_t g = s_base + q;
        if (g < CAP) keys[g] = s_stage[q];
    }
}

// ---------------- exact rank sort + fused decode (numpy f32 rounding, no FMA) ----------------
__global__ void k_rankdec(const uint64_t* __restrict__ keys, const uint32_t* __restrict__ ctrs,
                          const float* __restrict__ anchors, const float* __restrict__ reg,
                          float* __restrict__ topScore, float* __restrict__ boxes,
                          float* __restrict__ areas) {
    __shared__ uint64_t s_keys[256];
    uint32_t M = ctrs[0]; if (M > CAP) M = CAP;
    int j = blockIdx.x * blockDim.x + threadIdx.x;
    uint64_t myKey = (j < (int)M) ? keys[j] : 0ull;
    uint32_t rank = 0;
    for (uint32_t base = 0; base < M; base += 256) {
        uint32_t idx = base + threadIdx.x;
        s_keys[threadIdx.x] = (idx < M) ? keys[idx] : 0ull;
        __syncthreads();
        uint32_t lim = min(256u, M - base);
        for (uint32_t q = 0; q < lim; q++)
            rank += (s_keys[q] > myKey) ? 1u : 0u;
        __syncthreads();
    }
    if (j < (int)M && rank < KSEL) {
        uint32_t srcIdx = ~((uint32_t)(myKey & 0xFFFFFFFFull));
        topScore[rank] = __uint_as_float((uint32_t)(myKey >> 32));
        float4 a = *reinterpret_cast<const float4*>(&anchors[(size_t)srcIdx * 4]);
        float4 dd = *reinterpret_cast<const float4*>(&reg[(size_t)srcIdx * 4]);
        float d0 = __fmul_rn(dd.x, 0.1f);
        float d1 = __fmul_rn(dd.y, 0.1f);
        float d2 = __fmul_rn(dd.z, 0.2f);
        float d3 = __fmul_rn(dd.w, 0.2f);
        float w  = __fsub_rn(a.z, a.x);
        float h  = __fsub_rn(a.w, a.y);
        float cx = __fadd_rn(a.x, __fmul_rn(0.5f, w));
        float cy = __fadd_rn(a.y, __fmul_rn(0.5f, h));
        float pcx = __fadd_rn(cx, __fmul_rn(d0, w));
        float pcy = __fadd_rn(cy, __fmul_rn(d1, h));
        float pw = __fmul_rn((float)exp((double)d2), w);
        float ph = __fmul_rn((float)exp((double)d3), h);
        float x0 = __fsub_rn(pcx, __fmul_rn(0.5f, pw));
        float y0 = __fsub_rn(pcy, __fmul_rn(0.5f, ph));
        float x1 = __fadd_rn(pcx, __fmul_rn(0.5f, pw));
        float y1 = __fadd_rn(pcy, __fmul_rn(0.5f, ph));
        x0 = fminf(fmaxf(x0, 0.0f), 1024.0f);
        y0 = fminf(fmaxf(y0, 0.0f), 1024.0f);
        x1 = fminf(fmaxf(x1, 0.0f), 1024.0f);
        y1 = fminf(fmaxf(y1, 0.0f), 1024.0f);
        *reinterpret_cast<float4*>(&boxes[(size_t)rank * 4]) = make_float4(x0, y0, x1, y1);
        areas[rank] = __fmul_rn(__fsub_rn(x1, x0), __fsub_rn(y1, y0));
    }
}

// ---------------- pairwise suppression bitmask; lower-triangle blocks write 0 ----------------
__global__ void k_mask(const float* __restrict__ boxes, const float* __restrict__ areas,
                       unsigned long long* __restrict__ rowmask) {
    int bi = blockIdx.y, bj = blockIdx.x;
    int t = threadIdx.x;
    if (bj < bi) {  // zero-fill so reduce can AND rows unguarded
        rowmask[(size_t)(bi * 64 + t) * 64 + bj] = 0ull;
        return;
    }
    __shared__ float s_box[64][4];
    __shared__ float s_area[64];
    int r0 = bi * 64 + t;
    s_box[t][0] = boxes[r0 * 4 + 0];
    s_box[t][1] = boxes[r0 * 4 + 1];
    s_box[t][2] = boxes[r0 * 4 + 2];
    s_box[t][3] = boxes[r0 * 4 + 3];
    s_area[t] = areas[r0];
    __syncthreads();
    int j = bj * 64 + t;
    float jx0 = boxes[j * 4 + 0], jy0 = boxes[j * 4 + 1], jx1 = boxes[j * 4 + 2], jy1 = boxes[j * 4 + 3];
    float ja = areas[j];
    unsigned long long myword = 0ull;
    #pragma unroll 4
    for (int r = 0; r < 64; r++) {
        int i = bi * 64 + r;
        float w = __fsub_rn(fminf(s_box[r][2], jx1), fmaxf(s_box[r][0], jx0));
        float h = __fsub_rn(fminf(s_box[r][3], jy1), fmaxf(s_box[r][1], jy0));
        w = fmaxf(w, 0.0f); h = fmaxf(h, 0.0f);
        float inter = __fmul_rn(w, h);
        float denom = __fadd_rn(__fsub_rn(__fadd_rn(s_area[r], ja), inter), 1e-8f);
        float iou = __fdiv_rn(inter, denom);
        bool sup = (iou > IOU_THR) && (j > i);
        unsigned long long b = __ballot(sup);
        if (t == r) myword = b;
    }
    rowmask[(size_t)(bi * 64 + t) * 64 + bj] = myword;
}

// ---------------- block-diagonal greedy NMS reduce + fused output ----------------
// 1 wave; lane w owns keep word w. Per block: 16 speculative row loads (indices
// from pre-phase-1 keep word, a superset of final alive) are FORCED concurrent
// via inline asm: volatile global_load_dwordx2 issues, then one s_waitcnt asm
// holding all 16 buffers as "+v" operands AND kw as a tied "=s" pass-through --
// the allocator must keep 32 VGPRs live (R9: VGPR=36 proved the compiler
// serialized them) and the wait can't move above phase-1. Diag words are
// pre-gathered to LDS (lgkmcnt domain, not drained by the per-block vmcnt).
#define EXTRACT(s) \
    idx##s = rr ? (uint32_t)__builtin_ctzll(rr) : 63u; rr &= rr - 1;
#define LOADA(s) \
    asm volatile("global_load_dwordx2 %0, %1, off" \
                 : "=v"(v##s) : "v"(baseaddr + (uint64_t)idx##s * 512ull));
#define ORV(s) \
    acc |= v##s & ((uint64_t)0 - ((kwv >> idx##s) & 1ull));

__global__ __launch_bounds__(64, 1) void k_reduce(const float* __restrict__ topScore,
                         const unsigned long long* __restrict__ rowmask,
                         const float* __restrict__ boxes,
                         const int* __restrict__ Hp, const int* __restrict__ Wp,
                         float* __restrict__ out) {
    __shared__ uint64_t s_diag[4096];   // [block b][lane] = row (64b+lane)'s word b
    int w = threadIdx.x;  // 0..63
    uint64_t keep = 0ull;
    #pragma unroll
    for (int c = 0; c < 64; c += 4) {
        float4 s4 = *reinterpret_cast<const float4*>(&topScore[w * 64 + c]);
        keep |= ((uint64_t)(s4.x > 0.0f) << (c + 0))
             |  ((uint64_t)(s4.y > 0.0f) << (c + 1))
             |  ((uint64_t)(s4.z > 0.0f) << (c + 2))
             |  ((uint64_t)(s4.w > 0.0f) << (c + 3));
    }

    // prologue: gather all diagonal words into LDS (4 static groups of 16)
    #pragma unroll
    for (int g = 0; g < 4; g++) {
        uint64_t tt[16];
        #pragma unroll
        for (int k2 = 0; k2 < 16; k2++) {
            int rb = g * 16 + k2;
            tt[k2] = rowmask[(size_t)(rb * 64 + w) * 64 + rb];
        }
        #pragma unroll
        for (int k2 = 0; k2 < 16; k2++) {
            int rb = g * 16 + k2;
            s_diag[rb * 64 + w] = tt[k2];
        }
    }

    for (int b = 0; b < 64; b++) {
        uint64_t baseaddr = (uint64_t)(uintptr_t)(rowmask + (size_t)(b * 64) * 64 + w);
        uint64_t kb = readlane64(keep, b);
        uint64_t diag = s_diag[b * 64 + w];          // lgkmcnt domain

        // extract up to 16 alive-before indices (wave-uniform SALU chain)
        uint64_t rr = kb;
        uint32_t idx0, idx1, idx2, idx3, idx4, idx5, idx6, idx7;
        uint32_t idx8, idx9, idx10, idx11, idx12, idx13, idx14, idx15;
        EXTRACT(0) EXTRACT(1) EXTRACT(2) EXTRACT(3)
        EXTRACT(4) EXTRACT(5) EXTRACT(6) EXTRACT(7)
        EXTRACT(8) EXTRACT(9) EXTRACT(10) EXTRACT(11)
        EXTRACT(12) EXTRACT(13) EXTRACT(14) EXTRACT(15)

        // issue the 16 speculative row loads (volatile asm: order pinned)
        uint64_t v0, v1, v2, v3, v4, v5, v6, v7;
        uint64_t v8, v9, v10, v11, v12, v13, v14, v15;
        LOADA(0) LOADA(1) LOADA(2) LOADA(3)
        LOADA(4) LOADA(5) LOADA(6) LOADA(7)
        LOADA(8) LOADA(9) LOADA(10) LOADA(11)
        LOADA(12) LOADA(13) LOADA(14) LOADA(15)
        __builtin_amdgcn_sched_barrier(0);  // phase-1 must not hoist above issue

        // phase 1: scalar within-block suppression (runs under the load shadow)
        uint64_t kw = kb;
        uint64_t rem = kw;
        while (rem) {
            int i = __builtin_ctzll(rem);
            rem &= rem - 1;
            uint64_t row = readlane64(diag, i);
            kw &= ~row;
            rem &= ~row;
        }

        // drain the 16 loads; kw passes through so ORs can't float above,
        // and the wait can't move above phase-1
        uint64_t kwv;
        asm volatile("s_waitcnt vmcnt(0)"
            : "=s"(kwv), "+v"(v0), "+v"(v1), "+v"(v2), "+v"(v3),
              "+v"(v4), "+v"(v5), "+v"(v6), "+v"(v7),
              "+v"(v8), "+v"(v9), "+v"(v10), "+v"(v11),
              "+v"(v12), "+v"(v13), "+v"(v14), "+v"(v15)
            : "0"(kw));

        // phase 2: masked OR of the 16 concurrent rows
        uint64_t acc = 0ull;
        ORV(0) ORV(1) ORV(2) ORV(3)
        ORV(4) ORV(5) ORV(6) ORV(7)
        ORV(8) ORV(9) ORV(10) ORV(11)
        ORV(12) ORV(13) ORV(14) ORV(15)

        // overflow: alive-before rows beyond the first 16 (early blocks only)
        const unsigned long long* base = rowmask + (size_t)(b * 64) * 64 + w;
        uint64_t rem2 = rr & kwv;
        while (rem2) {
            int i0 = __builtin_ctzll(rem2); uint64_t r = rem2 & (rem2 - 1);
            int i1 = r ? __builtin_ctzll(r) : i0; r = r ? (r & (r - 1)) : r;
            int i2 = r ? __builtin_ctzll(r) : i0; r = r ? (r & (r - 1)) : r;
            int i3 = r ? __builtin_ctzll(r) : i0; r = r ? (r & (r - 1)) : r;
            int i4 = r ? __builtin_ctzll(r) : i0; r = r ? (r & (r - 1)) : r;
            int i5 = r ? __builtin_ctzll(r) : i0; r = r ? (r & (r - 1)) : r;
            int i6 = r ? __builtin_ctzll(r) : i0; r = r ? (r & (r - 1)) : r;
            int i7 = r ? __builtin_ctzll(r) : i0; r = r ? (r & (r - 1)) : r;
            rem2 = r;
            uint64_t r0 = base[(size_t)i0 * 64];
            uint64_t r1 = base[(size_t)i1 * 64];
            uint64_t r2 = base[(size_t)i2 * 64];
            uint64_t r3 = base[(size_t)i3 * 64];
            uint64_t r4 = base[(size_t)i4 * 64];
            uint64_t r5 = base[(size_t)i5 * 64];
            uint64_t r6 = base[(size_t)i6 * 64];
            uint64_t r7 = base[(size_t)i7 * 64];
            acc |= (r0 | r1) | (r2 | r3) | ((r4 | r5) | (r6 | r7));
        }

        keep &= ~acc;   // lower-tri words are zero rows; lane b reproduces kw
    }

    // fused output: lane w owns rows [w*64, w*64+64)
    float sx = (float)((double)Wp[0] / 1024.0);
    float sy = (float)((double)Hp[0] / 1024.0);
    for (int c = 0; c < 64; c++) {
        int k = w * 64 + c;
        float f = ((keep >> c) & 1ull) ? 1.0f : 0.0f;
        float4 bx = *reinterpret_cast<const float4*>(&boxes[(size_t)k * 4]);
        out[k * 5 + 0] = __fmul_rn(__fmul_rn(bx.x, sx), f);
        out[k * 5 + 1] = __fmul_rn(__fmul_rn(bx.y, sy), f);
        out[k * 5 + 2] = __fmul_rn(__fmul_rn(bx.z, sx), f);
        out[k * 5 + 3] = __fmul_rn(__fmul_rn(bx.w, sy), f);
        out[k * 5 + 4] = __fmul_rn(topScore[k], f);
    }
}

extern "C" void kernel_launch(void* const* d_in, const int* in_sizes, int n_in,
                              void* d_out, int out_size, void* d_ws, size_t ws_size,
                              hipStream_t stream) {
    (void)in_sizes; (void)n_in; (void)out_size; (void)ws_size;
    const float4* cls4   = (const float4*)d_in[0];
    const float* reg     = (const float*)d_in[1];
    const float* anchors = (const float*)d_in[2];
    const int* Hp        = (const int*)d_in[3];
    const int* Wp        = (const int*)d_in[4];
    float* out = (float*)d_out;

    char* ws = (char*)d_ws;
    size_t off = 0;
    auto alloc = [&](size_t bytes) {
        char* p = ws + off;
        off = (off + bytes + 255) & ~(size_t)255;
        return p;
    };
    uint32_t* hist   = (uint32_t*)alloc(BINS * 4);
    uint32_t* ctrs   = (uint32_t*)alloc(64);
    uint64_t* keys   = (uint64_t*)alloc((size_t)CAP * 8);
    float* topScore  = (float*)alloc(KSEL * 4);
    float* boxes     = (float*)alloc(KSEL * 4 * 4);
    float* areas     = (float*)alloc(KSEL * 4);
    unsigned long long* rowmask = (unsigned long long*)alloc((size_t)KSEL * 64 * 8);

    k_init<<<16, 256, 0, stream>>>(hist, ctrs, topScore);
    k_hist<<<STREAM_BLOCKS, 256, 0, stream>>>(cls4, hist);
    k_thresh<<<1, 1024, 0, stream>>>(hist, ctrs);
    k_gather<<<STREAM_BLOCKS, 256, 0, stream>>>(cls4, ctrs, keys);
    k_rankdec<<<CAP / 256, 256, 0, stream>>>(keys, ctrs, anchors, reg, topScore, boxes, areas);
    dim3 mg(64, 64);
    k_mask<<<mg, 64, 0, stream>>>(boxes, areas, rowmask);
    k_reduce<<<1, 64, 0, stream>>>(topScore, rowmask, boxes, Hp, Wp, out);
}

// Round 11
// 243.655 us; speedup vs baseline: 1.0106x; 1.0106x over previous
//
#include <hip/hip_runtime.h>
#include <cstdint>

#define N_TOT 1572864
#define KSEL 4096
#define CAP 8192
#define BINS 4096
#define SCORE_THR 0.5f
#define IOU_THR 0.1f
#define STREAM_BLOCKS 512
#define STAGE 512

__device__ inline uint64_t readlane64(uint64_t v, int lane) {
    uint32_t lo = (uint32_t)__builtin_amdgcn_readlane((int)(uint32_t)v, lane);
    uint32_t hi = (uint32_t)__builtin_amdgcn_readlane((int)(uint32_t)(v >> 32), lane);
    return ((uint64_t)hi << 32) | lo;
}

// ---------------- init: zero hist/counters/topScore ----------------
__global__ void k_init(uint32_t* hist, uint32_t* ctrs, float* topScore) {
    int i = blockIdx.x * blockDim.x + threadIdx.x;
    if (i < BINS) hist[i] = 0;
    if (i < 16) ctrs[i] = 0;
    if (i < KSEL) topScore[i] = 0.0f;
}

// ---------------- histogram over score bits (scores in (0.5,1)), float4 stream ----------------
__global__ void k_hist(const float4* __restrict__ cls4, uint32_t* __restrict__ hist) {
    int i = blockIdx.x * blockDim.x + threadIdx.x;
    int stride = gridDim.x * blockDim.x;
    for (; i < N_TOT / 2; i += stride) {
        float4 c = cls4[i];
        if (c.y > SCORE_THR) {
            uint32_t bin = (__float_as_uint(c.y) - 0x3F000000u) >> 11;
            if (bin >= BINS) bin = BINS - 1;
            atomicAdd(&hist[bin], 1u);
        }
        if (c.w > SCORE_THR) {
            uint32_t bin = (__float_as_uint(c.w) - 0x3F000000u) >> 11;
            if (bin >= BINS) bin = BINS - 1;
            atomicAdd(&hist[bin], 1u);
        }
    }
}

// ---------------- find cutoff bin T: largest b with suffix(b) >= K ----------------
__global__ __launch_bounds__(1024) void k_thresh(const uint32_t* __restrict__ hist,
                                                 uint32_t* __restrict__ ctrs) {
    __shared__ uint32_t s_suf[1024];
    int t = threadIdx.x;
    uint32_t l0 = hist[t*4+0], l1 = hist[t*4+1], l2 = hist[t*4+2], l3 = hist[t*4+3];
    s_suf[t] = l0 + l1 + l2 + l3;
    __syncthreads();
    for (int off = 1; off < 1024; off <<= 1) {
        uint32_t v = (t + off < 1024) ? s_suf[t + off] : 0u;
        __syncthreads();
        s_suf[t] += v;
        __syncthreads();
    }
    uint32_t snext = (t < 1023) ? s_suf[t + 1] : 0u;
    uint32_t suf3 = snext + l3;
    uint32_t suf2 = suf3 + l2;
    uint32_t suf1 = suf2 + l1;
    uint32_t suf0 = suf1 + l0;
    uint32_t sufs[5] = {suf0, suf1, suf2, suf3, snext};
    #pragma unroll
    for (int q = 0; q < 4; q++) {
        if (sufs[q] >= KSEL && sufs[q+1] < KSEL) ctrs[1] = (uint32_t)(t*4 + q);
    }
    if (t == 0 && s_suf[0] < KSEL) ctrs[1] = 0;  // fewer than K candidates
}

// ---------------- gather candidates (bin >= T) via LDS staging; 1 global atomic/block ----------------
__global__ void k_gather(const float4* __restrict__ cls4, uint32_t* __restrict__ ctrs,
                         uint64_t* __restrict__ keys) {
    __shared__ uint32_t s_cnt;
    __shared__ uint32_t s_base;
    __shared__ uint64_t s_stage[STAGE];
    if (threadIdx.x == 0) s_cnt = 0;
    __syncthreads();

    uint32_t T = ctrs[1];
    uint32_t basebits = 0x3F000000u + (T << 11);
    int i = blockIdx.x * blockDim.x + threadIdx.x;
    int stride = gridDim.x * blockDim.x;
    for (; i < N_TOT / 2; i += stride) {
        float4 c = cls4[i];
        #pragma unroll
        for (int h = 0; h < 2; h++) {
            float s = h ? c.w : c.y;
            uint32_t idx = 2u * (uint32_t)i + (uint32_t)h;
            if (s > SCORE_THR) {
                uint32_t b = __float_as_uint(s);
                if (b >= basebits) {
                    uint64_t key = ((uint64_t)b << 32) | (uint32_t)(~idx);
                    uint32_t p = atomicAdd(&s_cnt, 1u);
                    if (p < STAGE) s_stage[p] = key;
                    else {  // overflow: rare fallback, correctness-preserving
                        uint32_t g = atomicAdd(&ctrs[0], 1u);
                        if (g < CAP) keys[g] = key;
                    }
                }
            }
        }
    }
    __syncthreads();
    uint32_t n = s_cnt < STAGE ? s_cnt : STAGE;
    if (threadIdx.x == 0 && n > 0) s_base = atomicAdd(&ctrs[0], n);
    __syncthreads();
    for (uint32_t q = threadIdx.x; q < n; q += blockDim.x) {
        uint32_t g = s_base + q;
        if (g < CAP) keys[g] = s_stage[q];
    }
}

// ---------------- exact rank sort + fused decode (numpy f32 rounding, no FMA) ----------------
__global__ void k_rankdec(const uint64_t* __restrict__ keys, const uint32_t* __restrict__ ctrs,
                          const float* __restrict__ anchors, const float* __restrict__ reg,
                          float* __restrict__ topScore, float* __restrict__ boxes,
                          float* __restrict__ areas) {
    __shared__ uint64_t s_keys[256];
    uint32_t M = ctrs[0]; if (M > CAP) M = CAP;
    int j = blockIdx.x * blockDim.x + threadIdx.x;
    uint64_t myKey = (j < (int)M) ? keys[j] : 0ull;
    uint32_t rank = 0;
    for (uint32_t base = 0; base < M; base += 256) {
        uint32_t idx = base + threadIdx.x;
        s_keys[threadIdx.x] = (idx < M) ? keys[idx] : 0ull;
        __syncthreads();
        uint32_t lim = min(256u, M - base);
        for (uint32_t q = 0; q < lim; q++)
            rank += (s_keys[q] > myKey) ? 1u : 0u;
        __syncthreads();
    }
    if (j < (int)M && rank < KSEL) {
        uint32_t srcIdx = ~((uint32_t)(myKey & 0xFFFFFFFFull));
        topScore[rank] = __uint_as_float((uint32_t)(myKey >> 32));
        float4 a = *reinterpret_cast<const float4*>(&anchors[(size_t)srcIdx * 4]);
        float4 dd = *reinterpret_cast<const float4*>(&reg[(size_t)srcIdx * 4]);
        float d0 = __fmul_rn(dd.x, 0.1f);
        float d1 = __fmul_rn(dd.y, 0.1f);
        float d2 = __fmul_rn(dd.z, 0.2f);
        float d3 = __fmul_rn(dd.w, 0.2f);
        float w  = __fsub_rn(a.z, a.x);
        float h  = __fsub_rn(a.w, a.y);
        float cx = __fadd_rn(a.x, __fmul_rn(0.5f, w));
        float cy = __fadd_rn(a.y, __fmul_rn(0.5f, h));
        float pcx = __fadd_rn(cx, __fmul_rn(d0, w));
        float pcy = __fadd_rn(cy, __fmul_rn(d1, h));
        float pw = __fmul_rn((float)exp((double)d2), w);
        float ph = __fmul_rn((float)exp((double)d3), h);
        float x0 = __fsub_rn(pcx, __fmul_rn(0.5f, pw));
        float y0 = __fsub_rn(pcy, __fmul_rn(0.5f, ph));
        float x1 = __fadd_rn(pcx, __fmul_rn(0.5f, pw));
        float y1 = __fadd_rn(pcy, __fmul_rn(0.5f, ph));
        x0 = fminf(fmaxf(x0, 0.0f), 1024.0f);
        y0 = fminf(fmaxf(y0, 0.0f), 1024.0f);
        x1 = fminf(fmaxf(x1, 0.0f), 1024.0f);
        y1 = fminf(fmaxf(y1, 0.0f), 1024.0f);
        *reinterpret_cast<float4*>(&boxes[(size_t)rank * 4]) = make_float4(x0, y0, x1, y1);
        areas[rank] = __fmul_rn(__fsub_rn(x1, x0), __fsub_rn(y1, y0));
    }
}

// ---------------- pairwise suppression bitmask; lower-triangle blocks write 0 ----------------
__global__ void k_mask(const float* __restrict__ boxes, const float* __restrict__ areas,
                       unsigned long long* __restrict__ rowmask) {
    int bi = blockIdx.y, bj = blockIdx.x;
    int t = threadIdx.x;
    if (bj < bi) {  // zero-fill so reduce can AND rows unguarded
        rowmask[(size_t)(bi * 64 + t) * 64 + bj] = 0ull;
        return;
    }
    __shared__ float s_box[64][4];
    __shared__ float s_area[64];
    int r0 = bi * 64 + t;
    s_box[t][0] = boxes[r0 * 4 + 0];
    s_box[t][1] = boxes[r0 * 4 + 1];
    s_box[t][2] = boxes[r0 * 4 + 2];
    s_box[t][3] = boxes[r0 * 4 + 3];
    s_area[t] = areas[r0];
    __syncthreads();
    int j = bj * 64 + t;
    float jx0 = boxes[j * 4 + 0], jy0 = boxes[j * 4 + 1], jx1 = boxes[j * 4 + 2], jy1 = boxes[j * 4 + 3];
    float ja = areas[j];
    unsigned long long myword = 0ull;
    #pragma unroll 4
    for (int r = 0; r < 64; r++) {
        int i = bi * 64 + r;
        float w = __fsub_rn(fminf(s_box[r][2], jx1), fmaxf(s_box[r][0], jx0));
        float h = __fsub_rn(fminf(s_box[r][3], jy1), fmaxf(s_box[r][1], jy0));
        w = fmaxf(w, 0.0f); h = fmaxf(h, 0.0f);
        float inter = __fmul_rn(w, h);
        float denom = __fadd_rn(__fsub_rn(__fadd_rn(s_area[r], ja), inter), 1e-8f);
        float iou = __fdiv_rn(inter, denom);
        bool sup = (iou > IOU_THR) && (j > i);
        unsigned long long b = __ballot(sup);
        if (t == r) myword = b;
    }
    rowmask[(size_t)(bi * 64 + t) * 64 + bj] = myword;
}

// ---------------- block-diagonal greedy NMS reduce + fused output ----------------
// 1 wave; lane w owns keep word w. Cross-block software pipeline: at the END of
// block b-1 (after keep update) the EXACT alive set of block b is extracted and
// its <=16 rows issued via asm volatile loads; block b's phase-1 + bookkeeping
// then runs under that latency, and a single s_waitcnt vmcnt(0) (tying the
// buffers + kw) drains it. Overflow (>16 alive in a block) is rare with exact
// extraction and runs with nothing else outstanding (compiler waits safe).
#define EXTP(s) i##s = rr ? (uint32_t)__builtin_ctzll(rr) : 63u; rr &= rr - 1ull;
#define ISSP(s) { uint32_t voff = (i##s << 9) + wo; \
    asm volatile("global_load_dwordx2 %0, %1, %2" \
                 : "=v"(v##s) : "v"(voff), "s"(nb_addr)); }
#define ORP(s)  acc |= v##s & ((uint64_t)0 - ((kwv >> i##s) & 1ull));
#define DO16(M) M(0) M(1) M(2) M(3) M(4) M(5) M(6) M(7) \
                M(8) M(9) M(10) M(11) M(12) M(13) M(14) M(15)

__global__ __launch_bounds__(64, 1) void k_reduce(const float* __restrict__ topScore,
                         const unsigned long long* __restrict__ rowmask,
                         const float* __restrict__ boxes,
                         const int* __restrict__ Hp, const int* __restrict__ Wp,
                         float* __restrict__ out) {
    __shared__ uint64_t s_diag[4096];   // [block b][lane] = row (64b+lane)'s word b
    int w = threadIdx.x;  // 0..63
    uint32_t wo = (uint32_t)w * 8u;
    uint64_t keep = 0ull;
    #pragma unroll
    for (int c = 0; c < 64; c += 4) {
        float4 s4 = *reinterpret_cast<const float4*>(&topScore[w * 64 + c]);
        keep |= ((uint64_t)(s4.x > 0.0f) << (c + 0))
             |  ((uint64_t)(s4.y > 0.0f) << (c + 1))
             |  ((uint64_t)(s4.z > 0.0f) << (c + 2))
             |  ((uint64_t)(s4.w > 0.0f) << (c + 3));
    }

    // prologue: gather all diagonal words into LDS (4 static groups of 16)
    #pragma unroll
    for (int g = 0; g < 4; g++) {
        uint64_t tt[16];
        #pragma unroll
        for (int k2 = 0; k2 < 16; k2++) {
            int rb = g * 16 + k2;
            tt[k2] = rowmask[(size_t)(rb * 64 + w) * 64 + rb];
        }
        #pragma unroll
        for (int k2 = 0; k2 < 16; k2++) {
            int rb = g * 16 + k2;
            s_diag[rb * 64 + w] = tt[k2];
        }
    }

    // batch state (persists across iterations)
    uint64_t v0, v1, v2, v3, v4, v5, v6, v7, v8, v9, v10, v11, v12, v13, v14, v15;
    uint32_t i0, i1, i2, i3, i4, i5, i6, i7, i8, i9, i10, i11, i12, i13, i14, i15;
    uint64_t rr;      // leftover (beyond 16) of the extracted set for the batch's block

    // prologue issue: block 0's exact alive set (initial keep word 0)
    {
        rr = readlane64(keep, 0);
        uint64_t nb_addr = (uint64_t)(uintptr_t)rowmask;  // block 0 base
        DO16(EXTP)
        DO16(ISSP)
        __builtin_amdgcn_sched_barrier(0);
    }

    for (int b = 0; b < 64; b++) {
        // phase 1: scalar within-block suppression (under the batch's load shadow)
        uint64_t kb = readlane64(keep, b);
        uint64_t diag = s_diag[b * 64 + w];
        uint64_t kw = kb, rem = kb;
        while (rem) {
            int i = __builtin_ctzll(rem);
            rem &= rem - 1ull;
            uint64_t row = readlane64(diag, i);
            kw &= ~row;
            rem &= ~row;
        }

        // drain this block's batch (issued at end of previous iteration)
        uint64_t kwv;
        asm volatile("s_waitcnt vmcnt(0)"
            : "=s"(kwv), "+v"(v0), "+v"(v1), "+v"(v2), "+v"(v3),
              "+v"(v4), "+v"(v5), "+v"(v6), "+v"(v7),
              "+v"(v8), "+v"(v9), "+v"(v10), "+v"(v11),
              "+v"(v12), "+v"(v13), "+v"(v14), "+v"(v15)
            : "0"(kw));

        // phase 2: masked OR of the batch rows
        uint64_t acc = 0ull;
        DO16(ORP)

        // overflow: alive rows beyond the first 16 (rare; nothing else outstanding)
        {
            const unsigned long long* base = rowmask + (size_t)b * 4096 + w;
            uint64_t rem2 = rr & kwv;
            while (rem2) {
                int o0 = __builtin_ctzll(rem2); uint64_t r = rem2 & (rem2 - 1);
                int o1 = r ? __builtin_ctzll(r) : o0; r = r ? (r & (r - 1)) : r;
                int o2 = r ? __builtin_ctzll(r) : o0; r = r ? (r & (r - 1)) : r;
                int o3 = r ? __builtin_ctzll(r) : o0; r = r ? (r & (r - 1)) : r;
                int o4 = r ? __builtin_ctzll(r) : o0; r = r ? (r & (r - 1)) : r;
                int o5 = r ? __builtin_ctzll(r) : o0; r = r ? (r & (r - 1)) : r;
                int o6 = r ? __builtin_ctzll(r) : o0; r = r ? (r & (r - 1)) : r;
                int o7 = r ? __builtin_ctzll(r) : o0; r = r ? (r & (r - 1)) : r;
                rem2 = r;
                uint64_t r0 = base[(size_t)o0 * 64];
                uint64_t r1 = base[(size_t)o1 * 64];
                uint64_t r2 = base[(size_t)o2 * 64];
                uint64_t r3 = base[(size_t)o3 * 64];
                uint64_t r4 = base[(size_t)o4 * 64];
                uint64_t r5 = base[(size_t)o5 * 64];
                uint64_t r6 = base[(size_t)o6 * 64];
                uint64_t r7 = base[(size_t)o7 * 64];
                acc |= (r0 | r1) | (r2 | r3) | ((r4 | r5) | (r6 | r7));
            }
        }

        keep &= ~acc;   // lower-tri words are zero rows; lane b reproduces kw

        // issue next block's batch from the EXACT post-update alive set
        {
            int nb = b + 1; if (nb > 63) nb = 63;   // b=63: harmless dummy batch
            rr = readlane64(keep, nb);
            uint64_t nb_addr = (uint64_t)(uintptr_t)(rowmask + (size_t)nb * 4096);
            DO16(EXTP)
            DO16(ISSP)
            __builtin_amdgcn_sched_barrier(0);
        }
    }

    // fused output: lane w owns rows [w*64, w*64+64)
    float sx = (float)((double)Wp[0] / 1024.0);
    float sy = (float)((double)Hp[0] / 1024.0);
    for (int c = 0; c < 64; c++) {
        int k = w * 64 + c;
        float f = ((keep >> c) & 1ull) ? 1.0f : 0.0f;
        float4 bx = *reinterpret_cast<const float4*>(&boxes[(size_t)k * 4]);
        out[k * 5 + 0] = __fmul_rn(__fmul_rn(bx.x, sx), f);
        out[k * 5 + 1] = __fmul_rn(__fmul_rn(bx.y, sy), f);
        out[k * 5 + 2] = __fmul_rn(__fmul_rn(bx.z, sx), f);
        out[k * 5 + 3] = __fmul_rn(__fmul_rn(bx.w, sy), f);
        out[k * 5 + 4] = __fmul_rn(topScore[k], f);
    }
}

extern "C" void kernel_launch(void* const* d_in, const int* in_sizes, int n_in,
                              void* d_out, int out_size, void* d_ws, size_t ws_size,
                              hipStream_t stream) {
    (void)in_sizes; (void)n_in; (void)out_size; (void)ws_size;
    const float4* cls4   = (const float4*)d_in[0];
    const float* reg     = (const float*)d_in[1];
    const float* anchors = (const float*)d_in[2];
    const int* Hp        = (const int*)d_in[3];
    const int* Wp        = (const int*)d_in[4];
    float* out = (float*)d_out;

    char* ws = (char*)d_ws;
    size_t off = 0;
    auto alloc = [&](size_t bytes) {
        char* p = ws + off;
        off = (off + bytes + 255) & ~(size_t)255;
        return p;
    };
    uint32_t* hist   = (uint32_t*)alloc(BINS * 4);
    uint32_t* ctrs   = (uint32_t*)alloc(64);
    uint64_t* keys   = (uint64_t*)alloc((size_t)CAP * 8);
    float* topScore  = (float*)alloc(KSEL * 4);
    float* boxes     = (float*)alloc(KSEL * 4 * 4);
    float* areas     = (float*)alloc(KSEL * 4);
    unsigned long long* rowmask = (unsigned long long*)alloc((size_t)KSEL * 64 * 8);

    k_init<<<16, 256, 0, stream>>>(hist, ctrs, topScore);
    k_hist<<<STREAM_BLOCKS, 256, 0, stream>>>(cls4, hist);
    k_thresh<<<1, 1024, 0, stream>>>(hist, ctrs);
    k_gather<<<STREAM_BLOCKS, 256, 0, stream>>>(cls4, ctrs, keys);
    k_rankdec<<<CAP / 256, 256, 0, stream>>>(keys, ctrs, anchors, reg, topScore, boxes, areas);
    dim3 mg(64, 64);
    k_mask<<<mg, 64, 0, stream>>>(boxes, areas, rowmask);
    k_reduce<<<1, 64, 0, stream>>>(topScore, rowmask, boxes, Hp, Wp, out);
}